// Round 1
// baseline (1067.600 us; speedup 1.0000x reference)
//
#include <hip/hip_runtime.h>
#include <hip/hip_bf16.h>

#define IN_CH 512
#define OUT_CH 64

// --- Stage 1: in-degree histogram (self-loop handled as +1 later) ---
__global__ void deg_kernel(const int* __restrict__ col, unsigned int* __restrict__ cnt, int E) {
    int e = blockIdx.x * blockDim.x + threadIdx.x;
    if (e < E) atomicAdd(&cnt[col[e]], 1u);
}

// --- Stage 2: dinv = rsqrt(deg), deg = cnt + 1 (self-loop) ---
__global__ void dinv_kernel(const unsigned int* __restrict__ cnt, float* __restrict__ dinv, int N) {
    int i = blockIdx.x * blockDim.x + threadIdx.x;
    if (i < N) dinv[i] = rsqrtf((float)(cnt[i] + 1u));
}

// --- Stage 3: h = x @ W. One wave per row; lane = output channel. ---
// Row base pointer is wave-uniform (readfirstlane) so x loads go through the
// scalar path; W[k*64+lane] is lane-coalesced and L2-resident (128 KB).
__global__ void gemm_kernel(const float* __restrict__ x, const float* __restrict__ W,
                            float* __restrict__ h, int N) {
    int wave = (blockIdx.x * blockDim.x + threadIdx.x) >> 6;
    int lane = threadIdx.x & 63;
    if (wave >= N) return;
    int row = __builtin_amdgcn_readfirstlane(wave);
    const float* __restrict__ xr = x + (size_t)row * IN_CH;
    float acc = 0.0f;
#pragma unroll 8
    for (int k = 0; k < IN_CH; ++k) {
        acc = fmaf(xr[k], W[k * OUT_CH + lane], acc);
    }
    h[(size_t)row * OUT_CH + lane] = acc;
}

// --- Stage 4: edge scatter. One wave per edge; 64 lanes = 64 channels. ---
__global__ void scatter_kernel(const int* __restrict__ ei, const float* __restrict__ h,
                               const float* __restrict__ dinv, float* __restrict__ agg, int E) {
    int e = (int)((blockIdx.x * (unsigned long long)blockDim.x + threadIdx.x) >> 6);
    int lane = threadIdx.x & 63;
    if (e >= E) return;
    int row = __builtin_amdgcn_readfirstlane(ei[e]);
    int col = __builtin_amdgcn_readfirstlane(ei[E + e]);
    float norm = dinv[row] * dinv[col];
    float v = h[(size_t)row * OUT_CH + lane] * norm;
    unsafeAtomicAdd(&agg[(size_t)col * OUT_CH + lane], v);
}

// --- Stage 5: add self-loop + bias, log_softmax per row (wave-wide) ---
__global__ void finish_kernel(const float* __restrict__ agg, const float* __restrict__ h,
                              const float* __restrict__ dinv, const float* __restrict__ b,
                              float* __restrict__ out, int N) {
    int i = (int)((blockIdx.x * (unsigned long long)blockDim.x + threadIdx.x) >> 6);
    int lane = threadIdx.x & 63;
    if (i >= N) return;
    float di = dinv[i];
    size_t base = (size_t)i * OUT_CH;
    float v = agg[base + lane] + h[base + lane] * di * di + b[lane];
    // wave-wide max (width 64)
    float m = v;
#pragma unroll
    for (int off = 32; off > 0; off >>= 1) m = fmaxf(m, __shfl_xor(m, off, 64));
    float ex = expf(v - m);
    float s = ex;
#pragma unroll
    for (int off = 32; off > 0; off >>= 1) s += __shfl_xor(s, off, 64);
    out[base + lane] = v - m - logf(s);
}

extern "C" void kernel_launch(void* const* d_in, const int* in_sizes, int n_in,
                              void* d_out, int out_size, void* d_ws, size_t ws_size,
                              hipStream_t stream) {
    const float* x  = (const float*)d_in[0];
    const int*   ei = (const int*)d_in[1];
    const float* W  = (const float*)d_in[2];
    const float* b  = (const float*)d_in[3];
    float* out = (float*)d_out;

    const int N = in_sizes[0] / IN_CH;   // 100000
    const int E = in_sizes[1] / 2;       // 1600000

    char* ws = (char*)d_ws;
    float*        agg  = (float*)ws;                                   // N*64 f32
    unsigned int* cnt  = (unsigned int*)(ws + (size_t)N * OUT_CH * 4); // N u32
    float*        dinv = (float*)(ws + (size_t)N * OUT_CH * 4 + (size_t)N * 4);
    float*        h    = (float*)(ws + (size_t)N * OUT_CH * 4 + (size_t)N * 8);

    // zero agg + cnt in one memset (graph-capture-safe)
    hipMemsetAsync(ws, 0, (size_t)N * OUT_CH * 4 + (size_t)N * 4, stream);

    deg_kernel<<<(E + 255) / 256, 256, 0, stream>>>(ei + E, cnt, E);
    dinv_kernel<<<(N + 255) / 256, 256, 0, stream>>>(cnt, dinv, N);
    gemm_kernel<<<(N + 3) / 4, 256, 0, stream>>>(x, W, h, N);
    scatter_kernel<<<(E + 3) / 4, 256, 0, stream>>>(ei, h, dinv, agg, E);
    finish_kernel<<<(N + 3) / 4, 256, 0, stream>>>(agg, h, dinv, b, out, N);
}

// Round 2
// 579.781 us; speedup vs baseline: 1.8414x; 1.8414x over previous
//
#include <hip/hip_runtime.h>
#include <hip/hip_bf16.h>

#define IN_CH 512
#define OUT_CH 64
#define SCAN_CHUNK 2048   // 256 threads * 8 elements

typedef __attribute__((ext_vector_type(8))) short short8;
typedef __attribute__((ext_vector_type(4))) float f32x4;

static __device__ __forceinline__ short bf16bits(float f) {
    __hip_bfloat16 h = __float2bfloat16(f);
    return *reinterpret_cast<short*>(&h);
}

// --- in-degree histogram over col ---
__global__ void deg_kernel(const int* __restrict__ col, unsigned int* __restrict__ cnt, int E) {
    int e = blockIdx.x * blockDim.x + threadIdx.x;
    if (e < E) atomicAdd(&cnt[col[e]], 1u);
}

// --- dinv = rsqrt(deg+1)  (self-loop) ---
__global__ void dinv_kernel(const unsigned int* __restrict__ cnt, float* __restrict__ dinv, int N) {
    int i = blockIdx.x * blockDim.x + threadIdx.x;
    if (i < N) dinv[i] = rsqrtf((float)(cnt[i] + 1u));
}

// --- W[512][64] fp32 -> Wt[64][512] bf16 bits ---
__global__ void wt_kernel(const float* __restrict__ W, unsigned short* __restrict__ Wt) {
    int i = blockIdx.x * blockDim.x + threadIdx.x;   // 32768
    int k = i >> 6, n = i & 63;
    Wt[n * IN_CH + k] = (unsigned short)bf16bits(W[i]);
}

// --- scan stage A: per-2048-chunk exclusive scan of cnt -> rowptr (local), block totals ---
__global__ void scan_a(const unsigned int* __restrict__ cnt, unsigned int* __restrict__ rowptr,
                       unsigned int* __restrict__ blockSums, int N) {
    __shared__ unsigned int wsum[4];
    int t = threadIdx.x, b = blockIdx.x;
    int base = b * SCAN_CHUNK + t * 8;
    unsigned int v[8], p[8];
    unsigned int run = 0;
#pragma unroll
    for (int j = 0; j < 8; ++j) {
        v[j] = (base + j < N) ? cnt[base + j] : 0u;
        p[j] = run;
        run += v[j];
    }
    unsigned int s = run;        // thread total
    unsigned int si = s;         // wave inclusive scan
#pragma unroll
    for (int off = 1; off < 64; off <<= 1) {
        unsigned int o = __shfl_up(si, off, 64);
        if ((t & 63) >= off) si += o;
    }
    if ((t & 63) == 63) wsum[t >> 6] = si;
    __syncthreads();
    unsigned int woff = 0;
    int w = t >> 6;
    for (int k = 0; k < w; ++k) woff += wsum[k];
    unsigned int exc = woff + si - s;   // exclusive prefix of this thread within block
#pragma unroll
    for (int j = 0; j < 8; ++j)
        if (base + j < N) rowptr[base + j] = exc + p[j];
    if (t == 255) blockSums[b] = woff + si;
}

// --- scan stage B: exclusive scan of 49 block totals (single wave) ---
__global__ void scan_b(const unsigned int* __restrict__ blockSums, unsigned int* __restrict__ blockOff, int nb) {
    int t = threadIdx.x;   // 64 threads
    unsigned int s = (t < nb) ? blockSums[t] : 0u;
    unsigned int si = s;
#pragma unroll
    for (int off = 1; off < 64; off <<= 1) {
        unsigned int o = __shfl_up(si, off, 64);
        if (t >= off) si += o;
    }
    blockOff[t] = si - s;
}

// --- fill CSR: srcIdx[segment(col)] = row ---
__global__ void fill_kernel(const int* __restrict__ ei, const unsigned int* __restrict__ rowptr,
                            const unsigned int* __restrict__ blockOff, unsigned int* __restrict__ cursor,
                            unsigned int* __restrict__ srcIdx, int E) {
    int e = blockIdx.x * blockDim.x + threadIdx.x;
    if (e >= E) return;
    int r = ei[e], c = ei[E + e];
    unsigned int pos = rowptr[c] + blockOff[c >> 11] + atomicAdd(&cursor[c], 1u);
    srcIdx[pos] = (unsigned int)r;
}

// --- MFMA bf16 GEMM: h = x @ W. One wave per 16 rows; 4 x (16x16) N-tiles. ---
__global__ void __launch_bounds__(256) gemm_mfma(const float* __restrict__ x,
                                                 const unsigned short* __restrict__ Wt,
                                                 float* __restrict__ h, int N) {
    int wid = (int)((blockIdx.x * (unsigned long long)blockDim.x + threadIdx.x) >> 6);
    int lane = threadIdx.x & 63;
    int row0 = wid * 16;
    if (row0 >= N) return;
    int m = lane & 15, q = lane >> 4;
    const float* xr = x + (size_t)(row0 + m) * IN_CH + q * 8;
    f32x4 acc[4];
#pragma unroll
    for (int t = 0; t < 4; ++t) acc[t] = (f32x4){0.f, 0.f, 0.f, 0.f};

    for (int kb = 0; kb < IN_CH; kb += 32) {
        f32x4 a0 = *(const f32x4*)(xr + kb);
        f32x4 a1 = *(const f32x4*)(xr + kb + 4);
        short8 af;
        af[0] = bf16bits(a0[0]); af[1] = bf16bits(a0[1]);
        af[2] = bf16bits(a0[2]); af[3] = bf16bits(a0[3]);
        af[4] = bf16bits(a1[0]); af[5] = bf16bits(a1[1]);
        af[6] = bf16bits(a1[2]); af[7] = bf16bits(a1[3]);
#pragma unroll
        for (int t = 0; t < 4; ++t) {
            short8 bf = *(const short8*)(Wt + (size_t)(t * 16 + m) * IN_CH + kb + q * 8);
            acc[t] = __builtin_amdgcn_mfma_f32_16x16x32_bf16(af, bf, acc[t], 0, 0, 0);
        }
    }
    // C/D layout: col = lane&15 (within tile), row = q*4 + reg
#pragma unroll
    for (int t = 0; t < 4; ++t)
#pragma unroll
        for (int r = 0; r < 4; ++r)
            h[(size_t)(row0 + q * 4 + r) * OUT_CH + t * 16 + m] = acc[t][r];
}

// --- fused gather + self-loop + bias + log_softmax ---
__global__ void __launch_bounds__(256) gather_kernel(const unsigned int* __restrict__ srcIdx,
                                                     const unsigned int* __restrict__ rowptr,
                                                     const unsigned int* __restrict__ blockOff,
                                                     const unsigned int* __restrict__ cnt,
                                                     const float* __restrict__ dinv,
                                                     const float* __restrict__ h,
                                                     const float* __restrict__ bias,
                                                     float* __restrict__ out, int N) {
    int node = (int)((blockIdx.x * (unsigned long long)blockDim.x + threadIdx.x) >> 6);
    int lane = threadIdx.x & 63;
    if (node >= N) return;
    float di = dinv[node];
    float acc = h[(size_t)node * OUT_CH + lane] * di * di;
    unsigned int start = rowptr[node] + blockOff[node >> 11];
    unsigned int len = cnt[node];
    unsigned int j = 0;
    for (; j + 2 <= len; j += 2) {
        unsigned int r0 = srcIdx[start + j], r1 = srcIdx[start + j + 1];
        float n0 = dinv[r0] * di, n1 = dinv[r1] * di;
        float h0 = h[(size_t)r0 * OUT_CH + lane];
        float h1 = h[(size_t)r1 * OUT_CH + lane];
        acc = fmaf(h0, n0, acc);
        acc = fmaf(h1, n1, acc);
    }
    if (j < len) {
        unsigned int r = srcIdx[start + j];
        acc = fmaf(h[(size_t)r * OUT_CH + lane], dinv[r] * di, acc);
    }
    float v = acc + bias[lane];
    float mx = v;
#pragma unroll
    for (int off = 32; off > 0; off >>= 1) mx = fmaxf(mx, __shfl_xor(mx, off, 64));
    float ex = expf(v - mx);
    float s = ex;
#pragma unroll
    for (int off = 32; off > 0; off >>= 1) s += __shfl_xor(s, off, 64);
    out[(size_t)node * OUT_CH + lane] = v - mx - logf(s);
}

extern "C" void kernel_launch(void* const* d_in, const int* in_sizes, int n_in,
                              void* d_out, int out_size, void* d_ws, size_t ws_size,
                              hipStream_t stream) {
    const float* x  = (const float*)d_in[0];
    const int*   ei = (const int*)d_in[1];
    const float* W  = (const float*)d_in[2];
    const float* b  = (const float*)d_in[3];
    float* out = (float*)d_out;

    const int N = in_sizes[0] / IN_CH;   // 100000
    const int E = in_sizes[1] / 2;       // 1600000
    const int NBLK = (N + SCAN_CHUNK - 1) / SCAN_CHUNK;  // 49

    char* ws = (char*)d_ws;
    size_t o = 0;
    unsigned int* cnt      = (unsigned int*)(ws + o); o += (size_t)N * 4;
    unsigned int* cursor   = (unsigned int*)(ws + o); o += (size_t)N * 4;
    unsigned int* rowptr   = (unsigned int*)(ws + o); o += (size_t)N * 4;
    unsigned int* blockSums= (unsigned int*)(ws + o); o += 64 * 4;
    unsigned int* blockOff = (unsigned int*)(ws + o); o += 64 * 4;
    float*        dinv     = (float*)(ws + o);        o += (size_t)N * 4;
    unsigned int* srcIdx   = (unsigned int*)(ws + o); o += (size_t)E * 4;
    unsigned short* Wt     = (unsigned short*)(ws + o); o += (size_t)IN_CH * OUT_CH * 2;
    float*        h        = (float*)(ws + o);        o += (size_t)N * OUT_CH * 4;

    // zero cnt + cursor in one shot (adjacent)
    hipMemsetAsync(cnt, 0, (size_t)N * 8, stream);

    wt_kernel<<<(IN_CH * OUT_CH + 255) / 256, 256, 0, stream>>>(W, Wt);
    deg_kernel<<<(E + 255) / 256, 256, 0, stream>>>(ei + E, cnt, E);
    dinv_kernel<<<(N + 255) / 256, 256, 0, stream>>>(cnt, dinv, N);
    scan_a<<<NBLK, 256, 0, stream>>>(cnt, rowptr, blockSums, N);
    scan_b<<<1, 64, 0, stream>>>(blockSums, blockOff, NBLK);
    gemm_mfma<<<((N + 15) / 16 + 3) / 4, 256, 0, stream>>>(x, Wt, h, N);
    fill_kernel<<<(E + 255) / 256, 256, 0, stream>>>(ei, rowptr, blockOff, cursor, srcIdx, E);
    gather_kernel<<<(N + 3) / 4, 256, 0, stream>>>(srcIdx, rowptr, blockOff, cnt, dinv, h, b, out, N);
}

// Round 3
// 523.552 us; speedup vs baseline: 2.0391x; 1.1074x over previous
//
#include <hip/hip_runtime.h>
#include <hip/hip_bf16.h>

#define IN_CH 512
#define OUT_CH 64
#define SCAN_CHUNK 2048   // 256 threads * 8 elements

typedef __attribute__((ext_vector_type(8))) short short8;
typedef __attribute__((ext_vector_type(4))) float f32x4;

static __device__ __forceinline__ unsigned short bf16bits(float f) {
    __hip_bfloat16 h = __float2bfloat16(f);
    return *reinterpret_cast<unsigned short*>(&h);
}
static __device__ __forceinline__ float bflo(unsigned int u) {  // low ushort as bf16 -> f32
    return __uint_as_float(u << 16);
}
static __device__ __forceinline__ float bfhi(unsigned int u) {  // high ushort as bf16 -> f32
    return __uint_as_float(u & 0xffff0000u);
}

// --- W[512][64] -> Wt[64][512] bf16; block 128 zeroes the sentinel hs row N ---
__global__ void wt_kernel(const float* __restrict__ W, unsigned short* __restrict__ Wt,
                          unsigned short* __restrict__ hs, int N) {
    if (blockIdx.x == 128) {
        if (threadIdx.x < OUT_CH) hs[(size_t)N * OUT_CH + threadIdx.x] = 0;
        return;
    }
    int i = blockIdx.x * 256 + threadIdx.x;   // 32768
    int k = i >> 6, n = i & 63;
    Wt[n * IN_CH + k] = bf16bits(W[i]);
}

// --- init srcIdx to sentinel N (padding rows point at the zero row) ---
__global__ void init_srcIdx(unsigned int* __restrict__ srcIdx, unsigned int total4, unsigned int sent) {
    unsigned int i = blockIdx.x * 256 + threadIdx.x;
    if (i < total4) {
        uint4 v = {sent, sent, sent, sent};
        ((uint4*)srcIdx)[i] = v;
    }
}

// --- in-degree histogram over col, 4 edges/thread ---
__global__ void deg_kernel(const int* __restrict__ col, unsigned int* __restrict__ cnt, int E) {
    int E4 = E >> 2;
    int i = blockIdx.x * 256 + threadIdx.x;
    if (i < E4) {
        int4 c = ((const int4*)col)[i];
        atomicAdd(&cnt[c.x], 1u);
        atomicAdd(&cnt[c.y], 1u);
        atomicAdd(&cnt[c.z], 1u);
        atomicAdd(&cnt[c.w], 1u);
    } else if (i == E4) {
        for (int e = E4 * 4; e < E; ++e) atomicAdd(&cnt[col[e]], 1u);
    }
}

// --- scan A: per-chunk exclusive scan of PADDED counts (pad to mult of 8); also dinv ---
__global__ void scan_a(const unsigned int* __restrict__ cnt, float* __restrict__ dinv,
                       unsigned int* __restrict__ rowptr, unsigned int* __restrict__ blockSums, int N) {
    __shared__ unsigned int wsum[4];
    int t = threadIdx.x, b = blockIdx.x;
    int base = b * SCAN_CHUNK + t * 8;
    unsigned int p[8];
    unsigned int run = 0;
#pragma unroll
    for (int j = 0; j < 8; ++j) {
        unsigned int v = (base + j < N) ? cnt[base + j] : 0u;
        if (base + j < N) dinv[base + j] = rsqrtf((float)(v + 1u));
        p[j] = run;
        run += (v + 7u) & ~7u;   // padded count
    }
    unsigned int s = run;
    unsigned int si = s;
#pragma unroll
    for (int off = 1; off < 64; off <<= 1) {
        unsigned int o = __shfl_up(si, off, 64);
        if ((t & 63) >= off) si += o;
    }
    if ((t & 63) == 63) wsum[t >> 6] = si;
    __syncthreads();
    unsigned int woff = 0;
    int w = t >> 6;
    for (int k = 0; k < w; ++k) woff += wsum[k];
    unsigned int exc = woff + si - s;
#pragma unroll
    for (int j = 0; j < 8; ++j)
        if (base + j < N) rowptr[base + j] = exc + p[j];
    if (t == 255) blockSums[b] = woff + si;
}

// --- scan B: exclusive scan of block totals (single wave, nb<=64) ---
__global__ void scan_b(const unsigned int* __restrict__ blockSums, unsigned int* __restrict__ blockOff, int nb) {
    int t = threadIdx.x;
    unsigned int s = (t < nb) ? blockSums[t] : 0u;
    unsigned int si = s;
#pragma unroll
    for (int off = 1; off < 64; off <<= 1) {
        unsigned int o = __shfl_up(si, off, 64);
        if (t >= off) si += o;
    }
    blockOff[t] = si - s;
}

// --- MFMA bf16 GEMM: hs = (x @ W) * dinv[row], stored bf16. One wave per 16 rows. ---
__global__ void __launch_bounds__(256) gemm_mfma(const float* __restrict__ x,
                                                 const unsigned short* __restrict__ Wt,
                                                 const float* __restrict__ dinv,
                                                 unsigned short* __restrict__ hs, int N) {
    int wid = (int)((blockIdx.x * (unsigned long long)blockDim.x + threadIdx.x) >> 6);
    int lane = threadIdx.x & 63;
    int row0 = wid * 16;
    if (row0 >= N) return;
    int m = lane & 15, q = lane >> 4;
    const float* xr = x + (size_t)(row0 + m) * IN_CH + q * 8;
    f32x4 acc[4];
#pragma unroll
    for (int t = 0; t < 4; ++t) acc[t] = (f32x4){0.f, 0.f, 0.f, 0.f};

    for (int kb = 0; kb < IN_CH; kb += 32) {
        f32x4 a0 = *(const f32x4*)(xr + kb);
        f32x4 a1 = *(const f32x4*)(xr + kb + 4);
        short8 af;
        af[0] = (short)bf16bits(a0[0]); af[1] = (short)bf16bits(a0[1]);
        af[2] = (short)bf16bits(a0[2]); af[3] = (short)bf16bits(a0[3]);
        af[4] = (short)bf16bits(a1[0]); af[5] = (short)bf16bits(a1[1]);
        af[6] = (short)bf16bits(a1[2]); af[7] = (short)bf16bits(a1[3]);
#pragma unroll
        for (int t = 0; t < 4; ++t) {
            short8 bf = *(const short8*)(Wt + (size_t)(t * 16 + m) * IN_CH + kb + q * 8);
            acc[t] = __builtin_amdgcn_mfma_f32_16x16x32_bf16(af, bf, acc[t], 0, 0, 0);
        }
    }
    // C/D layout: col = lane&15, row (within 16) = q*4 + reg
#pragma unroll
    for (int r = 0; r < 4; ++r) {
        float dr = dinv[row0 + q * 4 + r];
#pragma unroll
        for (int t = 0; t < 4; ++t)
            hs[(size_t)(row0 + q * 4 + r) * OUT_CH + t * 16 + m] = bf16bits(acc[t][r] * dr);
    }
}

// --- fill CSR: srcIdx[padded segment(col)] = row, 4 edges/thread ---
__global__ void fill_kernel(const int* __restrict__ ei, const unsigned int* __restrict__ rowptr,
                            const unsigned int* __restrict__ blockOff, unsigned int* __restrict__ cursor,
                            unsigned int* __restrict__ srcIdx, int E) {
    int E4 = E >> 2;
    int i = blockIdx.x * 256 + threadIdx.x;
    if (i < E4) {
        int4 r = ((const int4*)ei)[i];
        int4 c = ((const int4*)(ei + E))[i];
        unsigned int pos;
        pos = rowptr[c.x] + blockOff[c.x >> 11] + atomicAdd(&cursor[c.x], 1u); srcIdx[pos] = (unsigned int)r.x;
        pos = rowptr[c.y] + blockOff[c.y >> 11] + atomicAdd(&cursor[c.y], 1u); srcIdx[pos] = (unsigned int)r.y;
        pos = rowptr[c.z] + blockOff[c.z >> 11] + atomicAdd(&cursor[c.z], 1u); srcIdx[pos] = (unsigned int)r.z;
        pos = rowptr[c.w] + blockOff[c.w >> 11] + atomicAdd(&cursor[c.w], 1u); srcIdx[pos] = (unsigned int)r.w;
    } else if (i == E4) {
        for (int e = E4 * 4; e < E; ++e) {
            int r = ei[e], c = ei[E + e];
            unsigned int pos = rowptr[c] + blockOff[c >> 11] + atomicAdd(&cursor[c], 1u);
            srcIdx[pos] = (unsigned int)r;
        }
    }
}

// --- fused gather + self + bias + log_softmax. One wave/node; half-waves cover 4 edges each. ---
__global__ void __launch_bounds__(256) gather_kernel(const unsigned int* __restrict__ srcIdx,
                                                     const unsigned int* __restrict__ rowptr,
                                                     const unsigned int* __restrict__ blockOff,
                                                     const unsigned int* __restrict__ cnt,
                                                     const float* __restrict__ dinv,
                                                     const unsigned short* __restrict__ hs,
                                                     const float* __restrict__ bias,
                                                     float* __restrict__ out, int N) {
    int node = (int)((blockIdx.x * (unsigned long long)blockDim.x + threadIdx.x) >> 6);
    int lane = threadIdx.x & 63;
    if (node >= N) return;
    int sub = lane >> 5, ch2 = lane & 31;   // lane covers channels 2*ch2, 2*ch2+1
    unsigned int start = rowptr[node] + blockOff[node >> 11];
    unsigned int iters = (cnt[node] + 7u) >> 3;   // 8 edges per iter (4 per half-wave)
    const uint4* sp = (const uint4*)(srcIdx + start + sub * 4);
    float acc0 = 0.f, acc1 = 0.f;
    for (unsigned int it = 0; it < iters; ++it) {
        uint4 iv = sp[it * 2];
        unsigned int u0 = *(const unsigned int*)(hs + (size_t)iv.x * OUT_CH + 2 * ch2);
        unsigned int u1 = *(const unsigned int*)(hs + (size_t)iv.y * OUT_CH + 2 * ch2);
        unsigned int u2 = *(const unsigned int*)(hs + (size_t)iv.z * OUT_CH + 2 * ch2);
        unsigned int u3 = *(const unsigned int*)(hs + (size_t)iv.w * OUT_CH + 2 * ch2);
        acc0 += bflo(u0) + bflo(u1) + bflo(u2) + bflo(u3);
        acc1 += bfhi(u0) + bfhi(u1) + bfhi(u2) + bfhi(u3);
    }
    acc0 += __shfl_xor(acc0, 32, 64);
    acc1 += __shfl_xor(acc1, 32, 64);
    // self-loop term: + hs[node]; whole thing scaled by dinv[node]
    unsigned int us = *(const unsigned int*)(hs + (size_t)node * OUT_CH + 2 * ch2);
    acc0 += bflo(us);
    acc1 += bfhi(us);
    float di = dinv[node];
    float2 bb = *(const float2*)(bias + 2 * ch2);
    float v0 = fmaf(acc0, di, bb.x);
    float v1 = fmaf(acc1, di, bb.y);
    // log_softmax over 64 channels; each half-wave holds all channels (2/lane over 32 lanes)
    float mx = fmaxf(v0, v1);
#pragma unroll
    for (int off = 16; off > 0; off >>= 1) mx = fmaxf(mx, __shfl_xor(mx, off, 64));
    float s = expf(v0 - mx) + expf(v1 - mx);
#pragma unroll
    for (int off = 16; off > 0; off >>= 1) s += __shfl_xor(s, off, 64);
    float ls = logf(s);
    if (sub == 0) {
        float2 o = {v0 - mx - ls, v1 - mx - ls};
        *(float2*)(out + (size_t)node * OUT_CH + 2 * ch2) = o;
    }
}

extern "C" void kernel_launch(void* const* d_in, const int* in_sizes, int n_in,
                              void* d_out, int out_size, void* d_ws, size_t ws_size,
                              hipStream_t stream) {
    const float* x  = (const float*)d_in[0];
    const int*   ei = (const int*)d_in[1];
    const float* W  = (const float*)d_in[2];
    const float* b  = (const float*)d_in[3];
    float* out = (float*)d_out;

    const int N = in_sizes[0] / IN_CH;   // 100000
    const int E = in_sizes[1] / 2;       // 1600000
    const int NBLK = (N + SCAN_CHUNK - 1) / SCAN_CHUNK;  // 49
    const unsigned int PADTOT = (unsigned int)E + 8u * (unsigned int)N;  // max padded entries
    const unsigned int TOT4 = (PADTOT + 3u) / 4u;

    char* ws = (char*)d_ws;
    size_t o = 0;
    unsigned int* cnt      = (unsigned int*)(ws + o); o += (size_t)N * 4;
    unsigned int* cursor   = (unsigned int*)(ws + o); o += (size_t)N * 4;
    unsigned int* rowptr   = (unsigned int*)(ws + o); o += (size_t)N * 4;
    unsigned int* blockSums= (unsigned int*)(ws + o); o += 256;
    unsigned int* blockOff = (unsigned int*)(ws + o); o += 256;
    float*        dinv     = (float*)(ws + o);        o += (size_t)N * 4;
    unsigned int* srcIdx   = (unsigned int*)(ws + o); o += (size_t)TOT4 * 16;
    unsigned short* Wt     = (unsigned short*)(ws + o); o += (size_t)IN_CH * OUT_CH * 2;
    unsigned short* hs     = (unsigned short*)(ws + o); o += (size_t)(N + 1) * OUT_CH * 2;

    // zero cnt + cursor (adjacent) in one memset
    hipMemsetAsync(cnt, 0, (size_t)N * 8, stream);

    wt_kernel<<<129, 256, 0, stream>>>(W, Wt, hs, N);
    init_srcIdx<<<(TOT4 + 255) / 256, 256, 0, stream>>>(srcIdx, TOT4, (unsigned int)N);
    deg_kernel<<<(E / 4 + 256) / 256, 256, 0, stream>>>(ei + E, cnt, E);
    scan_a<<<NBLK, 256, 0, stream>>>(cnt, dinv, rowptr, blockSums, N);
    scan_b<<<1, 64, 0, stream>>>(blockSums, blockOff, NBLK);
    gemm_mfma<<<((N + 15) / 16 * 64 + 255) / 256, 256, 0, stream>>>(x, Wt, dinv, hs, N);
    fill_kernel<<<(E / 4 + 256) / 256, 256, 0, stream>>>(ei, rowptr, blockOff, cursor, srcIdx, E);
    gather_kernel<<<((size_t)N * 64 + 255) / 256, 256, 0, stream>>>(srcIdx, rowptr, blockOff, cnt, dinv, hs, b, out, N);
}